// Round 11
// baseline (344.410 us; speedup 1.0000x reference)
//
#include <hip/hip_runtime.h>
#include <math.h>

#define BB 256
#define SS 256
#define NH 4

typedef __attribute__((ext_vector_type(8))) short bfrag;   // 8 bf16 (4 VGPRs)
typedef __attribute__((ext_vector_type(4))) float ffrag;   // 4 fp32 acc

__device__ inline unsigned short f2bf(float x) {
    unsigned u = __float_as_uint(x);
    u += 0x7FFF + ((u >> 16) & 1);          // round-to-nearest-even
    return (unsigned short)(u >> 16);
}
__device__ inline float bf2f(unsigned short h) {
    return __uint_as_float(((unsigned)h) << 16);
}
// Bit-twiddled RNE pack (R4..R10-proven numerics).
__device__ inline unsigned pack2(float a, float b) {
    return (unsigned)f2bf(a) | ((unsigned)f2bf(b) << 16);
}
union FragU { unsigned u[4]; bfrag b; };

// Load 8 consecutive fp32 -> bf16 MFMA frag in-register (same rounding as
// the old k0_cast, so Q/K/V/og numerics are bit-identical to R7..R10).
__device__ inline bfrag cvt8(const float* __restrict__ p) {
    const float4 a = *(const float4*)p;
    const float4 c = *(const float4*)(p + 4);
    FragU fu;
    fu.u[0] = pack2(a.x, a.y);
    fu.u[1] = pack2(a.z, a.w);
    fu.u[2] = pack2(c.x, c.y);
    fu.u[3] = pack2(c.z, c.w);
    return fu.b;
}

// Dynamic-LDS layout (element = unsigned short):
//   Qb  [256][40]  @ 0       (10240)
//   Kb  [256][40]  @ 10240   (10240)
//   Vt  [32][264]  @ 20480   ( 8448)
//   Gb  [256][34]  @ 28928   ( 8704)
//   ogL [256][136] @ 37632   (34816)
//   mask (f32[256]) @ byte 144896
#define QB_O   0
#define KB_O   10240
#define VT_O   20480
#define GB_O   28928
#define OGL_O  37632
#define MASK_BYTE_OFF 144896
#define DYN_LDS_BYTES 145920

// ---------------------------------------------------------------------------
// k_all: ONE kernel, one block per batch row b, 1024 thr = 16 waves.
// R11 = R10's structure with the register cap FIXED. R10's failure: dynamic
// LDS hides the 1-block/CU constraint from the compiler, whose occupancy
// heuristic targeted 8 waves/SIMD -> 64-VGPR cap -> ~300 MB scratch spills
// (code needs ~108, proven by R9). amdgpu_waves_per_eu(4,4) pins the
// allocator at 4 waves/SIMD = 128-VGPR budget: exactly 16 waves/block,
// 1 block/CU, no spill. R10 already proved occupancy doubles (47%) and
// correctness holds; this run isolates "16 waves WITHOUT spills".
// Also: Xf (X-row frags) hoisted out of the head loop — depends only on
// (w,b); R10 re-converted it 4x (16 VGPRs held instead, free at 128 budget).
//   for h in 0..3:  phase A (QKVG proj) ; phase B (attention) ; o*g -> ogL
//   proj: out = ogL x Wo^T + bo + addt  (wave (w&7)=c-tile, (w>>3)=row-half)
// ---------------------------------------------------------------------------
__global__
__attribute__((amdgpu_flat_work_group_size(1024, 1024), amdgpu_waves_per_eu(4, 4)))
void k_all(
    const float* __restrict__ X,             // fp32 [B][S][128]
    const float* __restrict__ W,             // fp32 [512][128]
    const float* __restrict__ gbias,         // [128]
    const float* __restrict__ mask,          // [B][S] (k-indexed)
    const float* __restrict__ bias,          // [NH][S][S]
    const float* __restrict__ Wo,            // fp32 [128][128]
    const float* __restrict__ bo,            // [128]
    const float* __restrict__ addt,          // [S][B][128] view
    float* __restrict__ out)                 // [S][B][128]
{
    const int b = blockIdx.x;
    const int t = threadIdx.x;
    const int w = t >> 6, lane = t & 63, l15 = lane & 15, quad = lane >> 4;

    extern __shared__ unsigned short smem[];
    unsigned short* Qb  = smem + QB_O;    // [s][c] stride 40
    unsigned short* Kb  = smem + KB_O;    // [s][c] stride 40
    unsigned short* Vt  = smem + VT_O;    // [c][s] stride 264
    unsigned short* Gb  = smem + GB_O;    // [s][c] stride 34
    unsigned short* ogL = smem + OGL_O;   // [s][f] stride 136
    float* maskLds = (float*)((char*)smem + MASK_BYTE_OFF);

    if (t < SS) maskLds[t] = (mask[b * SS + t] - 1.0f) * 1e9f;

    const float qscale = 0.17677669529663687f;  // 1/sqrt(32)

    const int srcA = l15 + ((quad & 1) * 2) * 16;
    const int srcB = srcA + 16;
    const bool hi = (quad >> 1) != 0;

    // X-row frags: head-invariant, loaded/converted ONCE (16 VGPRs held).
    bfrag Xf[4];
    {
        const int s = w * 16 + l15;
#pragma unroll
        for (int cc = 0; cc < 4; ++cc)
            Xf[cc] = cvt8(X + (size_t)(b * SS + s) * 128 + cc * 32 + quad * 8);
    }

    for (int h = 0; h < NH; ++h) {
        __syncthreads();   // prev head's phase B done (h=0: maskLds visible)

        // ---------------- phase A: QKVG projection for head h -------------
        // wave w owns s-rows [16w, 16w+16) — one 16-row tile.
        for (int half = 0; half < 2; ++half) {
            bfrag Wfr[4][4];
#pragma unroll
            for (int f4 = 0; f4 < 4; ++f4) {
                const int floc = (half * 4 + f4) * 16 + l15;        // 0..127
                const int grow = (floc >> 5) * 128 + h * 32 + (floc & 31);
#pragma unroll
                for (int cc = 0; cc < 4; ++cc)
                    Wfr[f4][cc] = cvt8(W + (size_t)grow * 128 + cc * 32 + quad * 8);
            }
#pragma unroll
            for (int f4 = 0; f4 < 4; ++f4) {
                ffrag D = {0.f, 0.f, 0.f, 0.f};
#pragma unroll
                for (int cc = 0; cc < 4; ++cc)
                    D = __builtin_amdgcn_mfma_f32_16x16x32_bf16(Xf[cc], Wfr[f4][cc], D, 0, 0, 0);
                const int ft = half * 4 + f4;
                const int fcol = ft * 16 + l15;
                const int srow0 = w * 16 + quad * 4;
                if (ft < 2) {
#pragma unroll
                    for (int r = 0; r < 4; ++r)
                        Qb[(srow0 + r) * 40 + fcol] = f2bf(D[r] * qscale);
                } else if (ft < 4) {
#pragma unroll
                    for (int r = 0; r < 4; ++r)
                        Kb[(srow0 + r) * 40 + (fcol - 32)] = f2bf(D[r]);
                } else if (ft < 6) {
                    const int base = (fcol - 64) * 264 + srow0;
                    *(unsigned*)&Vt[base]     = pack2(D[0], D[1]);
                    *(unsigned*)&Vt[base + 2] = pack2(D[2], D[3]);
                } else {
                    const int c = fcol - 96;
                    const float gb = gbias[h * 32 + c];
#pragma unroll
                    for (int r = 0; r < 4; ++r) {
                        const float g = 1.0f / (1.0f + __expf(-(D[r] + gb)));
                        Gb[(srow0 + r) * 34 + c] = f2bf(g);
                    }
                }
            }
        }
        __syncthreads();

        // ---------------- phase B: attention for head h --------------------
        // wave w owns q-tile w: q = 16w + l15 (one tile).
        bfrag Vfr[2][8];   // A-frags of V^T
#pragma unroll
        for (int ch = 0; ch < 2; ++ch)
#pragma unroll
            for (int ck = 0; ck < 8; ++ck)
                Vfr[ch][ck] = *(const bfrag*)&Vt[(ch * 16 + l15) * 264 + ck * 32 + quad * 8];

        {
            const int q = w * 16 + l15;
            const bfrag Qfr = *(const bfrag*)&Qb[q * 40 + quad * 8];

            ffrag S[16];
#pragma unroll
            for (int kt = 0; kt < 16; ++kt) {
                const bfrag Kfr = *(const bfrag*)&Kb[(kt * 16 + l15) * 40 + quad * 8];
                const ffrag z = {0.f, 0.f, 0.f, 0.f};
                S[kt] = __builtin_amdgcn_mfma_f32_16x16x32_bf16(Kfr, Qfr, z, 0, 0, 0);
            }

            const float* brow = bias + ((size_t)h * SS + q) * SS;
            float m = -1e30f;
#pragma unroll
            for (int kt = 0; kt < 16; ++kt) {
                const float4 bv = *(const float4*)(brow + kt * 16 + quad * 4);
                const float4 mv = *(const float4*)(maskLds + kt * 16 + quad * 4);
                S[kt][0] += bv.x + mv.x; S[kt][1] += bv.y + mv.y;
                S[kt][2] += bv.z + mv.z; S[kt][3] += bv.w + mv.w;
                m = fmaxf(m, fmaxf(fmaxf(S[kt][0], S[kt][1]), fmaxf(S[kt][2], S[kt][3])));
            }
            m = fmaxf(m, __shfl_xor(m, 16, 64));
            m = fmaxf(m, __shfl_xor(m, 32, 64));

            float l = 0.f;
            unsigned pk[16][2];
#pragma unroll
            for (int kt = 0; kt < 16; ++kt) {
                const float p0 = __expf(S[kt][0] - m);
                const float p1 = __expf(S[kt][1] - m);
                const float p2 = __expf(S[kt][2] - m);
                const float p3 = __expf(S[kt][3] - m);
                l += (p0 + p1) + (p2 + p3);
                pk[kt][0] = pack2(p0, p1);
                pk[kt][1] = pack2(p2, p3);
            }
            l += __shfl_xor(l, 16, 64);
            l += __shfl_xor(l, 32, 64);

            ffrag O[2];
            O[0] = (ffrag){0.f, 0.f, 0.f, 0.f};
            O[1] = (ffrag){0.f, 0.f, 0.f, 0.f};
#pragma unroll
            for (int ck = 0; ck < 8; ++ck) {
                const unsigned a0 = (unsigned)__shfl((int)pk[2 * ck][0],     srcA, 64);
                const unsigned b0 = (unsigned)__shfl((int)pk[2 * ck + 1][0], srcA, 64);
                const unsigned a1 = (unsigned)__shfl((int)pk[2 * ck][1],     srcA, 64);
                const unsigned b1 = (unsigned)__shfl((int)pk[2 * ck + 1][1], srcA, 64);
                const unsigned a2 = (unsigned)__shfl((int)pk[2 * ck][0],     srcB, 64);
                const unsigned b2 = (unsigned)__shfl((int)pk[2 * ck + 1][0], srcB, 64);
                const unsigned a3 = (unsigned)__shfl((int)pk[2 * ck][1],     srcB, 64);
                const unsigned b3 = (unsigned)__shfl((int)pk[2 * ck + 1][1], srcB, 64);
                FragU fu;
                fu.u[0] = hi ? b0 : a0;
                fu.u[1] = hi ? b1 : a1;
                fu.u[2] = hi ? b2 : a2;
                fu.u[3] = hi ? b3 : a3;
                O[0] = __builtin_amdgcn_mfma_f32_16x16x32_bf16(Vfr[0][ck], fu.b, O[0], 0, 0, 0);
                O[1] = __builtin_amdgcn_mfma_f32_16x16x32_bf16(Vfr[1][ck], fu.b, O[1], 0, 0, 0);
            }

            const float invl = 1.0f / l;
            const unsigned short* gr = &Gb[q * 34];
            unsigned* orow = (unsigned*)&ogL[q * 136 + h * 32];   // LDS
#pragma unroll
            for (int ch = 0; ch < 2; ++ch) {
                const int c0 = ch * 16 + quad * 4;
                const float v0 = O[ch][0] * invl * bf2f(gr[c0 + 0]);
                const float v1 = O[ch][1] * invl * bf2f(gr[c0 + 1]);
                const float v2 = O[ch][2] * invl * bf2f(gr[c0 + 2]);
                const float v3 = O[ch][3] * invl * bf2f(gr[c0 + 3]);
                orow[(c0 >> 1) + 0] = pack2(v0, v1);
                orow[(c0 >> 1) + 1] = pack2(v2, v3);
            }
        }
    }
    __syncthreads();   // ogL complete (all heads, all rows)

    // ---------------- proj: out = ogL x Wo^T + bo + addt -------------------
    // wave (w&7) owns c-tile, (w>>3) owns s-row half: 8 jt tiles per wave.
    const int crow = (w & 7) * 16 + l15;
    const int jt0  = (w >> 3) * 8;
    bfrag Wofr[4];
#pragma unroll
    for (int cc = 0; cc < 4; ++cc)
        Wofr[cc] = cvt8(Wo + (size_t)crow * 128 + cc * 32 + quad * 8);
    const float boc = bo[crow];

#pragma unroll
    for (int jj = 0; jj < 8; ++jj) {
        const int jt = jt0 + jj;
        bfrag Ab[4];
#pragma unroll
        for (int cc = 0; cc < 4; ++cc)
            Ab[cc] = *(const bfrag*)&ogL[(jt * 16 + l15) * 136 + cc * 32 + quad * 8];

        ffrag D = {0.f, 0.f, 0.f, 0.f};
#pragma unroll
        for (int cc = 0; cc < 4; ++cc)
            D = __builtin_amdgcn_mfma_f32_16x16x32_bf16(Ab[cc], Wofr[cc], D, 0, 0, 0);

#pragma unroll
        for (int r = 0; r < 4; ++r) {
            const int s = jt * 16 + quad * 4 + r;
            const size_t off = ((size_t)s * BB + b) * 128 + crow;
            out[off] = D[r] + boc + addt[off];
        }
    }
}

extern "C" void kernel_launch(void* const* d_in, const int* in_sizes, int n_in,
                              void* d_out, int out_size, void* d_ws, size_t ws_size,
                              hipStream_t stream) {
    const float* X     = (const float*)d_in[0];  // input_qkv [1,256,256,128]
    const float* mask  = (const float*)d_in[1];  // [1,256,1,1,256]
    const float* bias  = (const float*)d_in[2];  // [1,1,4,256,256]
    const float* addt  = (const float*)d_in[3];  // [1,256,256,128]
    const float* Wqkvg = (const float*)d_in[4];  // [512,128]
    const float* gbias = (const float*)d_in[5];  // [128]
    const float* Wo    = (const float*)d_in[6];  // [128,128]
    const float* bo    = (const float*)d_in[7];  // [128]
    float* out = (float*)d_out;

    // one-time opt-in to >64 KB dynamic LDS (host-side, capture-safe)
    static bool attrDone = false;
    if (!attrDone) {
        hipFuncSetAttribute((const void*)k_all,
                            hipFuncAttributeMaxDynamicSharedMemorySize,
                            DYN_LDS_BYTES);
        attrDone = true;
    }

    k_all<<<BB, 1024, DYN_LDS_BYTES, stream>>>(X, Wqkvg, gbias, mask, bias,
                                               Wo, bo, addt, out);
}

// Round 12
// 243.408 us; speedup vs baseline: 1.4150x; 1.4150x over previous
//
#include <hip/hip_runtime.h>
#include <math.h>

#define BB 256
#define SS 256
#define NH 4

typedef __attribute__((ext_vector_type(8))) short bfrag;   // 8 bf16 (4 VGPRs)
typedef __attribute__((ext_vector_type(4))) float ffrag;   // 4 fp32 acc

__device__ inline unsigned short f2bf(float x) {
    unsigned u = __float_as_uint(x);
    u += 0x7FFF + ((u >> 16) & 1);          // round-to-nearest-even
    return (unsigned short)(u >> 16);
}
__device__ inline float bf2f(unsigned short h) {
    return __uint_as_float(((unsigned)h) << 16);
}
// Bit-twiddled RNE pack (R4..R11-proven numerics).
__device__ inline unsigned pack2(float a, float b) {
    return (unsigned)f2bf(a) | ((unsigned)f2bf(b) << 16);
}
union FragU { unsigned u[4]; bfrag b; };

// ws layout (bf16 elements):
//   Xb  at 0         [B][S][128]   8388608
//   Wb  at 8388608   [512][128]      65536
//   Wob at 8454144   [128][128]      16384
//   og  at 8470528   [B][S][128]   8388608
#define XB_OFF  0
#define WB_OFF  8388608
#define WOB_OFF 8454144
#define OG_OFF  8470528

// ---------------------------------------------------------------------------
// k0: cast X, W_qkvg, W_o from fp32 to bf16 into workspace. 8 elems/thread.
// (~9 us measured via R5 ablation; X is read 4x by k_fused, so pre-casting
//  pays for itself — R5 evidence: fp32-in-kernel cost k_fused +34 us.)
// ---------------------------------------------------------------------------
__global__ __launch_bounds__(256) void k0_cast(
    const float* __restrict__ X, const float* __restrict__ W,
    const float* __restrict__ Wo, unsigned short* __restrict__ dst)
{
    const int gid = blockIdx.x * 256 + threadIdx.x;
    const int XN8 = 8388608 / 8, WN8 = 65536 / 8, WoN8 = 16384 / 8;
    const float* src;
    size_t soff, doff;
    if (gid < XN8)            { src = X;  soff = (size_t)gid * 8;                 doff = XB_OFF + soff; }
    else if (gid < XN8 + WN8) { src = W;  soff = (size_t)(gid - XN8) * 8;         doff = WB_OFF + soff; }
    else if (gid < XN8 + WN8 + WoN8) { src = Wo; soff = (size_t)(gid - XN8 - WN8) * 8; doff = WOB_OFF + soff; }
    else return;
    const float4 a = *(const float4*)(src + soff);
    const float4 b = *(const float4*)(src + soff + 4);
    unsigned r0 = pack2(a.x, a.y), r1 = pack2(a.z, a.w);
    unsigned r2 = pack2(b.x, b.y), r3 = pack2(b.z, b.w);
    uint4 o; o.x = r0; o.y = r1; o.z = r2; o.w = r3;
    *(uint4*)(dst + doff) = o;
}

// ---------------------------------------------------------------------------
// Fused QKVG projection + attention per (b,h). 256 thr = 4 waves; wave w owns
// s/q rows [64w, 64w+64). 16x16x32 bf16 MFMA layouts:
//   A/B-frag: row = lane&15, k = (lane>>4)*8 + j
//   C/D:      row = (lane>>4)*4 + reg, col = lane&15
// S^T = K·Q^T  (softmax over k = per-lane regs + shfl_xor(16/32) over cols).
//
// R12: PV shuffles ELIMINATED via MFMA k-permutation invariance.
// MFMA contracts sum_k A[m][k]B[k][n]; permuting k identically in BOTH frags
// preserves D. Pick pi(slot quad*8+j) = (j&4?16:0) + quad*4 + (j&3) — then
// the B-frag (P^T) slots are exactly the P values each lane already holds
// from S^T's C-layout (pk[2ck], pk[2ck+1] pack directly, ZERO cross-lane
// ops; was 64 ds_bpermute per qq). The matching A-side (V^T) permutation is
// applied at V-WRITE time in phase A: position ck*32 + quad*8 + (st&1)*4 + r
// with ck = w*2+(st>>1)  (still 2x contiguous 4 B writes, b128-aligned reads).
// O^T = V^T·P^T.  LDS total 74.5 KB -> 2 blocks/CU.  (R0-proven base: 112 us.)
// ---------------------------------------------------------------------------
__global__ __launch_bounds__(256, 2) void k_fused(
    const unsigned short* __restrict__ Xb,   // bf16 [B][S][128]
    const unsigned short* __restrict__ Wb,   // bf16 [512][128]
    const float* __restrict__ gbias,         // [128]
    const float* __restrict__ mask,          // [B][S] (k-indexed)
    const float* __restrict__ bias,          // [NH][S][S]
    unsigned short* __restrict__ og)         // bf16 [B][S][128]
{
    const int h = blockIdx.x, b = blockIdx.y;
    const int t = threadIdx.x;
    const int w = t >> 6, lane = t & 63, l15 = lane & 15, quad = lane >> 4;

    __shared__ unsigned short Qb[SS * 40];   // [s][c] stride 40
    __shared__ unsigned short Kb[SS * 40];
    __shared__ unsigned short Vt[32 * 264];  // [c][k-permuted] stride 264
    __shared__ unsigned short Gb[SS * 34];   // [s][c] stride 34
    __shared__ float maskLds[SS];

    maskLds[t] = (mask[b * SS + t] - 1.0f) * 1e9f;

    const float qscale = 0.17677669529663687f;  // 1/sqrt(32)

    // ---------------- phase A: QKVG projection for head h ----------------
    for (int half = 0; half < 2; ++half) {
        bfrag Wfr[4][4];
#pragma unroll
        for (int f4 = 0; f4 < 4; ++f4) {
            const int floc = (half * 4 + f4) * 16 + l15;            // 0..127
            const int grow = (floc >> 5) * 128 + h * 32 + (floc & 31);
#pragma unroll
            for (int cc = 0; cc < 4; ++cc)
                Wfr[f4][cc] = *(const bfrag*)(Wb + grow * 128 + cc * 32 + quad * 8);
        }
#pragma unroll
        for (int st = 0; st < 4; ++st) {
            const int s = w * 64 + st * 16 + l15;
            bfrag Xfr[4];
#pragma unroll
            for (int cc = 0; cc < 4; ++cc)
                Xfr[cc] = *(const bfrag*)(Xb + (b * SS + s) * 128 + cc * 32 + quad * 8);
#pragma unroll
            for (int f4 = 0; f4 < 4; ++f4) {
                ffrag D = {0.f, 0.f, 0.f, 0.f};
#pragma unroll
                for (int cc = 0; cc < 4; ++cc)
                    D = __builtin_amdgcn_mfma_f32_16x16x32_bf16(Xfr[cc], Wfr[f4][cc], D, 0, 0, 0);
                const int ft = half * 4 + f4;
                const int fcol = ft * 16 + l15;
                const int srow0 = w * 64 + st * 16 + quad * 4;
                if (ft < 2) {
#pragma unroll
                    for (int r = 0; r < 4; ++r)
                        Qb[(srow0 + r) * 40 + fcol] = f2bf(D[r] * qscale);
                } else if (ft < 4) {
#pragma unroll
                    for (int r = 0; r < 4; ++r)
                        Kb[(srow0 + r) * 40 + (fcol - 32)] = f2bf(D[r]);
                } else if (ft < 6) {
                    // k-permuted V^T store (R12): value k_P = srow0 + r goes
                    // to position ck*32 + quad*8 + (st&1)*4 + r, ck=w*2+(st>>1)
                    const int c = fcol - 64;
                    const int pos = (w * 2 + (st >> 1)) * 32 + quad * 8 + (st & 1) * 4;
                    const int base = c * 264 + pos;
                    *(unsigned*)&Vt[base]     = pack2(D[0], D[1]);
                    *(unsigned*)&Vt[base + 2] = pack2(D[2], D[3]);
                } else {
                    const int c = fcol - 96;
                    const float gb = gbias[h * 32 + c];
#pragma unroll
                    for (int r = 0; r < 4; ++r) {
                        const float g = 1.0f / (1.0f + __expf(-(D[r] + gb)));
                        Gb[(srow0 + r) * 34 + c] = f2bf(g);
                    }
                }
            }
        }
    }
    __syncthreads();

    // ---------------- phase B: attention ----------------
    bfrag Vfr[2][8];   // A-frags of V^T (k-permuted layout), loop-invariant
#pragma unroll
    for (int ch = 0; ch < 2; ++ch)
#pragma unroll
        for (int ck = 0; ck < 8; ++ck)
            Vfr[ch][ck] = *(const bfrag*)&Vt[(ch * 16 + l15) * 264 + ck * 32 + quad * 8];

    for (int qq = 0; qq < 4; ++qq) {
        const int q = w * 64 + qq * 16 + l15;
        const bfrag Qfr = *(const bfrag*)&Qb[q * 40 + quad * 8];

        ffrag S[16];
#pragma unroll
        for (int kt = 0; kt < 16; ++kt) {
            const bfrag Kfr = *(const bfrag*)&Kb[(kt * 16 + l15) * 40 + quad * 8];
            const ffrag z = {0.f, 0.f, 0.f, 0.f};
            S[kt] = __builtin_amdgcn_mfma_f32_16x16x32_bf16(Kfr, Qfr, z, 0, 0, 0);
        }

        // + bias + mask; running max (lane owns column q; rows k=kt*16+quad*4+r)
        const float* brow = bias + (h * SS + q) * SS;
        float m = -1e30f;
#pragma unroll
        for (int kt = 0; kt < 16; ++kt) {
            const float4 bv = *(const float4*)(brow + kt * 16 + quad * 4);
            const float4 mv = *(const float4*)(maskLds + kt * 16 + quad * 4);
            S[kt][0] += bv.x + mv.x; S[kt][1] += bv.y + mv.y;
            S[kt][2] += bv.z + mv.z; S[kt][3] += bv.w + mv.w;
            m = fmaxf(m, fmaxf(fmaxf(S[kt][0], S[kt][1]), fmaxf(S[kt][2], S[kt][3])));
        }
        m = fmaxf(m, __shfl_xor(m, 16, 64));
        m = fmaxf(m, __shfl_xor(m, 32, 64));

        float l = 0.f;
        unsigned pk[16][2];   // P packed bf16 pairs (r01, r23), C-layout
#pragma unroll
        for (int kt = 0; kt < 16; ++kt) {
            const float p0 = __expf(S[kt][0] - m);
            const float p1 = __expf(S[kt][1] - m);
            const float p2 = __expf(S[kt][2] - m);
            const float p3 = __expf(S[kt][3] - m);
            l += (p0 + p1) + (p2 + p3);
            pk[kt][0] = pack2(p0, p1);
            pk[kt][1] = pack2(p2, p3);
        }
        l += __shfl_xor(l, 16, 64);
        l += __shfl_xor(l, 32, 64);

        // PV: B-frag is the lane's OWN pk values under the k-permutation
        // (matching Vt's permuted store). No cross-lane ops.
        ffrag O[2];
        O[0] = (ffrag){0.f, 0.f, 0.f, 0.f};
        O[1] = (ffrag){0.f, 0.f, 0.f, 0.f};
#pragma unroll
        for (int ck = 0; ck < 8; ++ck) {
            FragU fu;
            fu.u[0] = pk[2 * ck][0];
            fu.u[1] = pk[2 * ck][1];
            fu.u[2] = pk[2 * ck + 1][0];
            fu.u[3] = pk[2 * ck + 1][1];
            O[0] = __builtin_amdgcn_mfma_f32_16x16x32_bf16(Vfr[0][ck], fu.b, O[0], 0, 0, 0);
            O[1] = __builtin_amdgcn_mfma_f32_16x16x32_bf16(Vfr[1][ck], fu.b, O[1], 0, 0, 0);
        }

        const float invl = 1.0f / l;
        const unsigned short* gr = &Gb[q * 34];
        unsigned* orow = (unsigned*)(og + (b * SS + q) * 128 + h * 32);
#pragma unroll
        for (int ch = 0; ch < 2; ++ch) {
            const int c0 = ch * 16 + quad * 4;
            const float v0 = O[ch][0] * invl * bf2f(gr[c0 + 0]);
            const float v1 = O[ch][1] * invl * bf2f(gr[c0 + 1]);
            const float v2 = O[ch][2] * invl * bf2f(gr[c0 + 2]);
            const float v3 = O[ch][3] * invl * bf2f(gr[c0 + 3]);
            orow[(c0 >> 1) + 0] = pack2(v0, v1);
            orow[(c0 >> 1) + 1] = pack2(v2, v3);
        }
    }
}

// ---------------------------------------------------------------------------
// k3: out[(s*B + j)*128 + c] = addt[same] + bo[c] + sum_f og[j][s][f]*Wo[c][f]
// R8-passed version: block (j, ih) = 64 s-rows, grid (256,4); og staging
// coalesced; MFMA -> fp32 LDS; coalesced float4 epilogue (half-wave per row).
// ---------------------------------------------------------------------------
__global__ __launch_bounds__(256) void k3_proj(
    const unsigned short* __restrict__ ogb,  // bf16 [B(j)][S(s)][128]
    const unsigned short* __restrict__ Wob,  // bf16 [128][128]
    const float* __restrict__ bo,            // [128]
    const float* __restrict__ addt,          // [S][B][128] view
    float* __restrict__ out)                 // [S][B][128]
{
    const int j = blockIdx.x, ih = blockIdx.y;   // ih: s-chunk of 64 rows
    const int t = threadIdx.x;
    const int w = t >> 6, lane = t & 63, l15 = lane & 15, quad = lane >> 4;

    __shared__ unsigned short OgS[64 * 136];  // [s_loc][f] stride 136, 17.4 KB
    __shared__ float OutS[64 * 132];          // [s_loc][c] stride 132, 33.8 KB

    // stage og[j][ih*64 + ss][0..128) -> LDS (coalesced; 4 threads per row)
    {
        const int ss = t >> 2;                // 0..63
        const int c32 = (t & 3) * 32;         // 0,32,64,96
        const unsigned short* src = ogb + (((size_t)j * SS + ih * 64 + ss) * 128) + c32;
        unsigned short* dst = &OgS[ss * 136 + c32];
#pragma unroll
        for (int u = 0; u < 4; ++u)
            *(uint4*)(dst + u * 8) = *(const uint4*)(src + u * 8);
    }

    // per-wave Wo B-frags: c rows (w*2+ctl)*16 + l15
    bfrag Wfr[2][4];
#pragma unroll
    for (int ctl = 0; ctl < 2; ++ctl) {
        const int crow = (w * 2 + ctl) * 16 + l15;
#pragma unroll
        for (int cc = 0; cc < 4; ++cc)
            Wfr[ctl][cc] = *(const bfrag*)(Wob + crow * 128 + cc * 32 + quad * 8);
    }
    const float bo0 = bo[(w * 2 + 0) * 16 + l15];
    const float bo1 = bo[(w * 2 + 1) * 16 + l15];

    __syncthreads();

#pragma unroll
    for (int jt = 0; jt < 4; ++jt) {
        bfrag Ab[4];
#pragma unroll
        for (int cc = 0; cc < 4; ++cc)
            Ab[cc] = *(const bfrag*)&OgS[(jt * 16 + l15) * 136 + cc * 32 + quad * 8];

        ffrag D0 = {0.f, 0.f, 0.f, 0.f};
        ffrag D1 = {0.f, 0.f, 0.f, 0.f};
#pragma unroll
        for (int cc = 0; cc < 4; ++cc) {
            D0 = __builtin_amdgcn_mfma_f32_16x16x32_bf16(Ab[cc], Wfr[0][cc], D0, 0, 0, 0);
            D1 = __builtin_amdgcn_mfma_f32_16x16x32_bf16(Ab[cc], Wfr[1][cc], D1, 0, 0, 0);
        }

        // D (+bo) -> LDS; C/D layout: row = quad*4+r (within 16), col = l15
        const int c0 = (w * 2 + 0) * 16 + l15;
        const int c1 = (w * 2 + 1) * 16 + l15;
#pragma unroll
        for (int r = 0; r < 4; ++r) {
            const int row = jt * 16 + quad * 4 + r;
            OutS[row * 132 + c0] = D0[r] + bo0;
            OutS[row * 132 + c1] = D1[r] + bo1;
        }
    }
    __syncthreads();

    // coalesced epilogue: half-wave per s-row, float4 ld/add/st
    {
        const int c4 = lane & 31;             // float4 index within the row
        const int rsub = t >> 5;              // 0..7 (wave, half)
#pragma unroll
        for (int v = 0; v < 8; ++v) {
            const int row = v * 8 + rsub;     // 0..63
            const int s = ih * 64 + row;
            const size_t off = ((size_t)s * BB + j) * 128 + c4 * 4;
            const float4 av = *(const float4*)(addt + off);
            const float4 dv = *(const float4*)&OutS[row * 132 + c4 * 4];
            float4 ov;
            ov.x = dv.x + av.x; ov.y = dv.y + av.y;
            ov.z = dv.z + av.z; ov.w = dv.w + av.w;
            *(float4*)(out + off) = ov;
        }
    }
}

extern "C" void kernel_launch(void* const* d_in, const int* in_sizes, int n_in,
                              void* d_out, int out_size, void* d_ws, size_t ws_size,
                              hipStream_t stream) {
    const float* X     = (const float*)d_in[0];  // input_qkv [1,256,256,128]
    const float* mask  = (const float*)d_in[1];  // [1,256,1,1,256]
    const float* bias  = (const float*)d_in[2];  // [1,1,4,256,256]
    const float* addt  = (const float*)d_in[3];  // [1,256,256,128]
    const float* Wqkvg = (const float*)d_in[4];  // [512,128]
    const float* gbias = (const float*)d_in[5];  // [128]
    const float* Wo    = (const float*)d_in[6];  // [128,128]
    const float* bo    = (const float*)d_in[7];  // [128]
    float* out = (float*)d_out;

    unsigned short* ws = (unsigned short*)d_ws;
    unsigned short* Xb  = ws + XB_OFF;
    unsigned short* Wb  = ws + WB_OFF;
    unsigned short* Wob = ws + WOB_OFF;
    unsigned short* og  = ws + OG_OFF;

    k0_cast<<<4136, 256, 0, stream>>>(X, Wqkvg, Wo, ws);
    k_fused<<<dim3(NH, BB), 256, 0, stream>>>(Xb, Wb, gbias, mask, bias, og);
    k3_proj<<<dim3(BB, 4), 256, 0, stream>>>(og, Wob, bo, addt, out);
}